// Round 5
// baseline (87.890 us; speedup 1.0000x reference)
//
#include <hip/hip_runtime.h>
#include <stdint.h>

// RelationTransform: out[i] = W[relation[i]] @ node_emb[i]
// N=32768, EMB=512, 16 relations, fp32 in/out.
// Prepass: histogram sort (ptok) + W->bf16 convert (ws).   [proven ~12us]
// GEMM: fused X-gather (fp32->reg->cvt->LDS), bf16 W staging, BK=64,
// 2-deep register prefetch (two static sets), 1 raw barrier per K-step,
// counted compiler vmcnt waits (loads stay in flight across barriers).

#define EMB 512
#define N_RELC 16
#define BM 128
#define BN 128
#define BK 64
#define NKT (EMB / BK)   // 8
#define LDP 72           // padded LDS row stride in bf16 (2-way-free reads)

typedef __attribute__((ext_vector_type(4))) float f32x4;
typedef __attribute__((ext_vector_type(8))) short bf16x8;

__device__ __forceinline__ unsigned short f2bf(float f) {
  unsigned int u = __float_as_uint(f);
  u += 0x7FFFu + ((u >> 16) & 1u);   // round-to-nearest-even
  return (unsigned short)(u >> 16);
}

__global__ void init_counts(int* cnt) {
  if (threadIdx.x < 32) cnt[threadIdx.x] = 0;
}

// Per-block LDS histogram rank; also fills ptok[0..padn) with -1.
__global__ __launch_bounds__(256) void histo_rank_fill(
    const int* __restrict__ rel, int* cnt, int* pos, int* ptok,
    int n, int padn) {
  __shared__ int lcnt[N_RELC];
  __shared__ int lbase[N_RELC];
  const int tid = threadIdx.x;
  if (tid < N_RELC) lcnt[tid] = 0;
  __syncthreads();
  const int i = blockIdx.x * blockDim.x + tid;
  if (i < padn) ptok[i] = -1;
  int r = 0, myrank = 0;
  if (i < n) { r = rel[i]; myrank = atomicAdd(&lcnt[r], 1); }
  __syncthreads();
  if (tid < N_RELC) lbase[tid] = atomicAdd(&cnt[tid], lcnt[tid]);
  __syncthreads();
  if (i < n) pos[i] = lbase[r] + myrank;
}

// Padded segment bases + tile table (1 block, 64 threads).
__global__ void prefix_tiles64(const int* __restrict__ cnt, int* pbase,
                               int* tinfo, int maxt) {
  __shared__ int sb[N_RELC + 1];
  __shared__ int st[N_RELC + 1];
  if (threadIdx.x == 0) {
    int acc = 0, t = 0;
    for (int r = 0; r < N_RELC; ++r) {
      sb[r] = acc; st[r] = t;
      const int nt = (cnt[r] + BM - 1) / BM;
      acc += nt * BM;
      t += nt;
    }
    sb[N_RELC] = acc; st[N_RELC] = t;
  }
  __syncthreads();
  for (int i = threadIdx.x; i <= N_RELC; i += blockDim.x) pbase[i] = sb[i];
  for (int x = threadIdx.x; x < maxt; x += blockDim.x) {
    int v = -1;
    #pragma unroll
    for (int r = 0; r < N_RELC; ++r)
      if (x >= st[r] && x < st[r + 1]) v = (r << 16) | (x - st[r]);
    tinfo[x] = v;
  }
}

__global__ __launch_bounds__(256) void scatter_ptok(
    const int* __restrict__ rel, const int* __restrict__ pos,
    const int* __restrict__ pbase, int* __restrict__ ptok, int n) {
  const int i = blockIdx.x * blockDim.x + threadIdx.x;
  if (i < n) ptok[pbase[rel[i]] + pos[i]] = i;
}

__global__ __launch_bounds__(256) void convert_W(const float* __restrict__ W,
                                                 unsigned short* __restrict__ Ws,
                                                 int welems) {
  const size_t i = ((size_t)blockIdx.x * 256 + threadIdx.x) * 8;
  if (i >= (size_t)welems) return;
  f32x4 a = *reinterpret_cast<const f32x4*>(W + i);
  f32x4 b = *reinterpret_cast<const f32x4*>(W + i + 4);
  bf16x8 o;
  o[0] = f2bf(a[0]); o[1] = f2bf(a[1]); o[2] = f2bf(a[2]); o[3] = f2bf(a[3]);
  o[4] = f2bf(b[0]); o[5] = f2bf(b[1]); o[6] = f2bf(b[2]); o[7] = f2bf(b[3]);
  *reinterpret_cast<bf16x8*>(Ws + i) = o;
}

// ---------------------------------------------------------------------------
// Grouped GEMM, 512 threads (8 waves, 2x4 wave grid; 64x32 output per wave).
// BK=64. Per-thread staging: srow=tid>>2 (0..127), kq=tid&3 (16-elem chunk).
//   A: 4x f32x4 gathered loads -> cvt -> 2x ds_write_b128 (bf16)
//   B: 2x bf16x8 loads (pre-converted Ws) -> 2x ds_write_b128
// Two static register sets (tile t -> set t&1); tile t's loads issue 2
// compute-phases before their use -> ~500cy latency cover.
// ---------------------------------------------------------------------------

#define DECL_SET(S) f32x4 a##S##0, a##S##1, a##S##2, a##S##3; bf16x8 b##S##0, b##S##1;

#define LOADR(S, KT)                                                           \
  {                                                                            \
    const float* ap_ = aptr + (KT) * BK;                                       \
    a##S##0 = *reinterpret_cast<const f32x4*>(ap_);                            \
    a##S##1 = *reinterpret_cast<const f32x4*>(ap_ + 4);                        \
    a##S##2 = *reinterpret_cast<const f32x4*>(ap_ + 8);                        \
    a##S##3 = *reinterpret_cast<const f32x4*>(ap_ + 12);                       \
    const unsigned short* bp_ = bptr + (KT) * BK;                              \
    b##S##0 = *reinterpret_cast<const bf16x8*>(bp_);                           \
    b##S##1 = *reinterpret_cast<const bf16x8*>(bp_ + 8);                       \
  }

#define WRITE(S)                                                               \
  {                                                                            \
    bf16x8 w0, w1;                                                             \
    w0[0] = (short)f2bf(a##S##0[0]); w0[1] = (short)f2bf(a##S##0[1]);          \
    w0[2] = (short)f2bf(a##S##0[2]); w0[3] = (short)f2bf(a##S##0[3]);          \
    w0[4] = (short)f2bf(a##S##1[0]); w0[5] = (short)f2bf(a##S##1[1]);          \
    w0[6] = (short)f2bf(a##S##1[2]); w0[7] = (short)f2bf(a##S##1[3]);          \
    w1[0] = (short)f2bf(a##S##2[0]); w1[1] = (short)f2bf(a##S##2[1]);          \
    w1[2] = (short)f2bf(a##S##2[2]); w1[3] = (short)f2bf(a##S##2[3]);          \
    w1[4] = (short)f2bf(a##S##3[0]); w1[5] = (short)f2bf(a##S##3[1]);          \
    w1[6] = (short)f2bf(a##S##3[2]); w1[7] = (short)f2bf(a##S##3[3]);          \
    *reinterpret_cast<bf16x8*>(&As[S][ldsoff])     = w0;                       \
    *reinterpret_cast<bf16x8*>(&As[S][ldsoff + 8]) = w1;                       \
    *reinterpret_cast<bf16x8*>(&Bs[S][ldsoff])     = b##S##0;                  \
    *reinterpret_cast<bf16x8*>(&Bs[S][ldsoff + 8]) = b##S##1;                  \
  }

#define COMPUTE(BUF)                                                           \
  {                                                                            \
    _Pragma("unroll")                                                          \
    for (int ks = 0; ks < 2; ++ks) {                                           \
      bf16x8 af[4], bfr[2];                                                    \
      _Pragma("unroll")                                                        \
      for (int m = 0; m < 4; ++m)                                              \
        af[m] = *reinterpret_cast<const bf16x8*>(                              \
            &As[BUF][(wr * 64 + m * 16 + lrow) * LDP + ks * 32 + gl * 8]);     \
      _Pragma("unroll")                                                        \
      for (int nn = 0; nn < 2; ++nn)                                           \
        bfr[nn] = *reinterpret_cast<const bf16x8*>(                            \
            &Bs[BUF][(wc * 32 + nn * 16 + lrow) * LDP + ks * 32 + gl * 8]);    \
      _Pragma("unroll")                                                        \
      for (int m = 0; m < 4; ++m)                                              \
        _Pragma("unroll")                                                      \
        for (int nn = 0; nn < 2; ++nn)                                         \
          acc[m][nn] = __builtin_amdgcn_mfma_f32_16x16x32_bf16(                \
              af[m], bfr[nn], acc[m][nn], 0, 0, 0);                            \
    }                                                                          \
  }

#define PIPE_BARRIER()                                                         \
  asm volatile("s_waitcnt lgkmcnt(0)" ::: "memory");                           \
  __builtin_amdgcn_s_barrier();                                                \
  __builtin_amdgcn_sched_barrier(0);

__global__ __launch_bounds__(512, 4) void grouped_gemm5(
    const float* __restrict__ X, const unsigned short* __restrict__ Ws,
    const int* __restrict__ pbase, const int* __restrict__ tinfo,
    const int* __restrict__ ptok, float* __restrict__ out)
{
  __shared__ unsigned short As[2][BM * LDP];   // 18 KB per buffer
  __shared__ unsigned short Bs[2][BN * LDP];

  const int info = tinfo[blockIdx.x];
  if (info < 0) return;
  const int r = info >> 16;
  const int mt = info & 0xFFFF;
  const int ct = blockIdx.y;
  const int prow0 = pbase[r] + mt * BM;

  const int tid = threadIdx.x;
  const int lane = tid & 63;
  const int wid = tid >> 6;
  const int wr = wid >> 2;          // 0..1 : 64-row band
  const int wc = wid & 3;           // 0..3 : 32-col band
  const int lrow = lane & 15;
  const int gl = lane >> 4;         // k-granule 0..3
  const int lrow4 = gl * 4;

  const int srow = tid >> 2;        // staging row 0..127
  const int kq = tid & 3;           // 16-elem chunk within BK
  const int ldsoff = srow * LDP + kq * 16;

  const int tokA = ptok[prow0 + srow];
  const float* aptr = X + (size_t)(tokA < 0 ? 0 : tokA) * EMB + kq * 16;
  const unsigned short* bptr =
      Ws + ((size_t)r * EMB + (size_t)(ct * BN + srow)) * EMB + kq * 16;

  f32x4 acc[4][2];
  const f32x4 vzero = {0.f, 0.f, 0.f, 0.f};
  #pragma unroll
  for (int m = 0; m < 4; ++m)
    #pragma unroll
    for (int nn = 0; nn < 2; ++nn) acc[m][nn] = vzero;

  DECL_SET(0)
  DECL_SET(1)

  // Prologue: tiles 0,1,2 in flight (tile t -> set t&1).
  LOADR(0, 0);
  WRITE(0);           // compiler waits tile-0 vmcnt via reg-dep
  LOADR(1, 1);
  LOADR(0, 2);
  PIPE_BARRIER();

  // Main loop: 4 unrolled pairs, fully static set/buffer indices.
  #pragma unroll
  for (int kt2 = 0; kt2 < 4; ++kt2) {
    const int kte = 2 * kt2;         // even tile -> LDS/set 0
    // --- even phase ---
    COMPUTE(0);
    WRITE(1);                        // tile kte+1 -> LDS1 (loads 2 phases old)
    if (kte + 3 <= NKT - 1) LOADR(1, kte + 3);
    PIPE_BARRIER();
    // --- odd phase ---
    COMPUTE(1);
    if (kte + 2 <= NKT - 1) {
      WRITE(0);                      // tile kte+2 -> LDS0
      if (kte + 4 <= NKT - 1) LOADR(0, kte + 4);
      PIPE_BARRIER();
    }
  }

  // Epilogue: D mapping col=lane&15, row=(lane>>4)*4+reg
  #pragma unroll
  for (int m = 0; m < 4; ++m) {
    const int base = prow0 + wr * 64 + m * 16 + lrow4;
    #pragma unroll
    for (int rg = 0; rg < 4; ++rg) {
      const int tok = ptok[base + rg];
      if (tok >= 0) {
        float* orow = out + (size_t)tok * EMB + ct * BN + wc * 32;
        #pragma unroll
        for (int nn = 0; nn < 2; ++nn)
          orow[nn * 16 + lrow] = acc[m][nn][rg];
      }
    }
  }
}

// Safety-net naive kernel (only if ws too small).
__global__ void naive_kernel(const float* __restrict__ X, const int* __restrict__ rel,
                             const float* __restrict__ W, float* __restrict__ out, int n) {
  int i = blockIdx.x;
  if (i >= n) return;
  int r = rel[i];
  const float* x = X + (size_t)i * EMB;
  const float* Wr = W + (size_t)r * EMB * EMB;
  for (int j = threadIdx.x; j < EMB; j += blockDim.x) {
    const float* w = Wr + (size_t)j * EMB;
    float s = 0.f;
    for (int k = 0; k < EMB; ++k) s += w[k] * x[k];
    out[(size_t)i * EMB + j] = s;
  }
}

extern "C" void kernel_launch(void* const* d_in, const int* in_sizes, int n_in,
                              void* d_out, int out_size, void* d_ws, size_t ws_size,
                              hipStream_t stream) {
  const float* X  = (const float*)d_in[0];
  const int* rel  = (const int*)d_in[1];
  const float* W  = (const float*)d_in[2];
  float* out      = (float*)d_out;
  const int n = in_sizes[1];
  const int welems = in_sizes[2];                 // n_rel * EMB * EMB
  const int padn = n + N_RELC * BM;
  const int maxt = (n + BM - 1) / BM + N_RELC;
  const int maxtp = ((maxt + 7) / 8) * 8;         // multiple of 8 for XCD co-location

  const size_t ints = (size_t)64 + n + padn + maxtp;
  const size_t offW = ((ints * sizeof(int) + 255) / 256) * 256;
  const size_t need = offW + (size_t)welems * 2;

  if (ws_size < need) {
    naive_kernel<<<n, 256, 0, stream>>>(X, rel, W, out, n);
    return;
  }

  int* cnt   = (int*)d_ws;       // 16 (+pad)
  int* pbase = cnt + 16;         // 17
  int* pos   = cnt + 64;         // n
  int* ptok  = pos + n;          // padn
  int* tinfo = ptok + padn;      // maxtp
  unsigned short* Ws = (unsigned short*)((char*)d_ws + offW);

  init_counts<<<1, 32, 0, stream>>>(cnt);
  histo_rank_fill<<<(padn + 255) / 256, 256, 0, stream>>>(rel, cnt, pos, ptok, n, padn);
  prefix_tiles64<<<1, 64, 0, stream>>>(cnt, pbase, tinfo, maxtp);
  scatter_ptok<<<(n + 255) / 256, 256, 0, stream>>>(rel, pos, pbase, ptok, n);
  convert_W<<<(welems / 8 + 255) / 256, 256, 0, stream>>>(W, Ws, welems);

  // grid.x = m-tiles (multiple of 8), grid.y = the 4 column tiles:
  // the 4 ct-blocks of one m-tile share blockIdx.x % 8 -> same XCD L2.
  dim3 grid(maxtp, EMB / BN);
  grouped_gemm5<<<grid, 512, 0, stream>>>(X, Ws, pbase, tinfo, ptok, out);
}

// Round 6
// 75.323 us; speedup vs baseline: 1.1668x; 1.1668x over previous
//
#include <hip/hip_runtime.h>
#include <stdint.h>

// RelationTransform: out[i] = W[relation[i]] @ node_emb[i]
// N=32768, EMB=512, 16 relations, fp32 in/out.
// Prepass: histogram sort -> ONE fused kernel (gather X->bf16 sorted Xs +
// ptok scatter, zero pads, convert W->bf16 Ws).
// GEMM: round-2-proven gload_lds 128x128 core + T3 2-phase double buffer
// (stage-before-compute, one vmcnt(0)+barrier per K-step), 32KB LDS ->
// ~4-5 blocks/CU so all ~1088 blocks are co-resident (TLP hides stalls).

#define EMB 512
#define N_RELC 16
#define BM 128
#define BN 128
#define BK 32
#define NKT (EMB / BK)   // 16

typedef __attribute__((ext_vector_type(4))) float f32x4;
typedef __attribute__((ext_vector_type(8))) short bf16x8;

__device__ __forceinline__ unsigned short f2bf(float f) {
  unsigned int u = __float_as_uint(f);
  u += 0x7FFFu + ((u >> 16) & 1u);   // round-to-nearest-even
  return (unsigned short)(u >> 16);
}

__device__ __forceinline__ void gload_lds16(const void* g, void* l) {
  __builtin_amdgcn_global_load_lds(
      (const __attribute__((address_space(1))) unsigned int*)(uintptr_t)g,
      (__attribute__((address_space(3))) unsigned int*)(uintptr_t)l, 16, 0, 0);
}

__global__ void init_counts(int* cnt) {
  if (threadIdx.x < 32) cnt[threadIdx.x] = 0;
}

// Per-block LDS histogram rank; also fills ptok[0..padn) with -1.
__global__ __launch_bounds__(256) void histo_rank_fill(
    const int* __restrict__ rel, int* cnt, int* pos, int* ptok,
    int n, int padn) {
  __shared__ int lcnt[N_RELC];
  __shared__ int lbase[N_RELC];
  const int tid = threadIdx.x;
  if (tid < N_RELC) lcnt[tid] = 0;
  __syncthreads();
  const int i = blockIdx.x * blockDim.x + tid;
  if (i < padn) ptok[i] = -1;
  int r = 0, myrank = 0;
  if (i < n) { r = rel[i]; myrank = atomicAdd(&lcnt[r], 1); }
  __syncthreads();
  if (tid < N_RELC) lbase[tid] = atomicAdd(&cnt[tid], lcnt[tid]);
  __syncthreads();
  if (i < n) pos[i] = lbase[r] + myrank;
}

// Padded segment bases + tile table (1 block, 64 threads).
__global__ void prefix_tiles64(const int* __restrict__ cnt, int* pbase,
                               int* tinfo, int maxt) {
  __shared__ int sb[N_RELC + 1];
  __shared__ int st[N_RELC + 1];
  if (threadIdx.x == 0) {
    int acc = 0, t = 0;
    for (int r = 0; r < N_RELC; ++r) {
      sb[r] = acc; st[r] = t;
      const int nt = (cnt[r] + BM - 1) / BM;
      acc += nt * BM;
      t += nt;
    }
    sb[N_RELC] = acc; st[N_RELC] = t;
  }
  __syncthreads();
  for (int i = threadIdx.x; i <= N_RELC; i += blockDim.x) pbase[i] = sb[i];
  for (int x = threadIdx.x; x < maxt; x += blockDim.x) {
    int v = -1;
    #pragma unroll
    for (int r = 0; r < N_RELC; ++r)
      if (x >= st[r] && x < st[r + 1]) v = (r << 16) | (x - st[r]);
    tinfo[x] = v;
  }
}

// Fused prepass: blocks [0,gb) gather X->Xs (+ptok), [gb,gb+16) zero Xs pads,
// [gb+16, ...) convert W->Ws.
__global__ __launch_bounds__(256) void prep_all(
    const float* __restrict__ X, const float* __restrict__ W,
    const int* __restrict__ rel, const int* __restrict__ pos,
    const int* __restrict__ pbase, const int* __restrict__ cnt,
    unsigned short* __restrict__ Xs, unsigned short* __restrict__ Ws,
    int* __restrict__ ptok, int n, int welems, int gb)
{
  const int b = blockIdx.x;
  if (b < gb) {                       // ---- gather+convert 4 token rows ----
    const int row = b * 4 + (threadIdx.x >> 6);
    const int lane = threadIdx.x & 63;
    if (row >= n) return;
    const int dst = pbase[rel[row]] + pos[row];
    if (lane == 0) ptok[dst] = row;
    const float* src = X + (size_t)row * EMB + lane * 8;
    f32x4 a = *reinterpret_cast<const f32x4*>(src);
    f32x4 c = *reinterpret_cast<const f32x4*>(src + 4);
    bf16x8 o;
    o[0] = f2bf(a[0]); o[1] = f2bf(a[1]); o[2] = f2bf(a[2]); o[3] = f2bf(a[3]);
    o[4] = f2bf(c[0]); o[5] = f2bf(c[1]); o[6] = f2bf(c[2]); o[7] = f2bf(c[3]);
    *reinterpret_cast<bf16x8*>(Xs + (size_t)dst * EMB + lane * 8) = o;
  } else if (b < gb + N_RELC) {       // ---- zero pad rows of relation r ----
    const int r = b - gb;
    const int start = pbase[r] + cnt[r];
    const int end = pbase[r + 1];
    const int nvec = (end - start) * (EMB / 8);
    unsigned short* p = Xs + (size_t)start * EMB;
    const bf16x8 z = {0, 0, 0, 0, 0, 0, 0, 0};
    for (int v = threadIdx.x; v < nvec; v += blockDim.x)
      *reinterpret_cast<bf16x8*>(p + (size_t)v * 8) = z;
  } else {                            // ---- convert W -> bf16 ----
    const size_t i = (((size_t)(b - gb - N_RELC)) * 256 + threadIdx.x) * 8;
    if (i >= (size_t)welems) return;
    f32x4 a = *reinterpret_cast<const f32x4*>(W + i);
    f32x4 c = *reinterpret_cast<const f32x4*>(W + i + 4);
    bf16x8 o;
    o[0] = f2bf(a[0]); o[1] = f2bf(a[1]); o[2] = f2bf(a[2]); o[3] = f2bf(a[3]);
    o[4] = f2bf(c[0]); o[5] = f2bf(c[1]); o[6] = f2bf(c[2]); o[7] = f2bf(c[3]);
    *reinterpret_cast<bf16x8*>(Ws + i) = o;
  }
}

// ---------------------------------------------------------------------------
// Grouped GEMM, 256 threads (4 waves, 2x2; 64x64 out per wave), BK=32.
// Double-buffered 8KB A/B tiles, gload_lds staging (2+2 loads per thread),
// stage(next) issued BEFORE compute(cur); one vmcnt(0)+lgkm(0)+barrier per
// K-step AFTER compute -> load latency hidden under 16 MFMAs + TLP.
// ---------------------------------------------------------------------------

#define STAGE(BUF, KT)                                                         \
  {                                                                            \
    const int kb_ = (KT) * BK;                                                 \
    gload_lds16(asrc0 + kb_, (char*)&As[BUF][0] + tid * 16);                   \
    gload_lds16(asrc1 + kb_, (char*)&As[BUF][0] + 4096 + tid * 16);            \
    gload_lds16(bsrc0 + kb_, (char*)&Bs[BUF][0] + tid * 16);                   \
    gload_lds16(bsrc1 + kb_, (char*)&Bs[BUF][0] + 4096 + tid * 16);            \
  }

#define COMPUTE(BUF)                                                           \
  {                                                                            \
    bf16x8 af[4], bfr[4];                                                      \
    _Pragma("unroll")                                                          \
    for (int m = 0; m < 4; ++m)                                                \
      af[m] = *reinterpret_cast<const bf16x8*>(                                \
          &As[BUF][(wr * 64 + m * 16 + lrow) * BK + gl * 8]);                  \
    _Pragma("unroll")                                                          \
    for (int nn = 0; nn < 4; ++nn)                                             \
      bfr[nn] = *reinterpret_cast<const bf16x8*>(                              \
          &Bs[BUF][(wc * 64 + nn * 16 + lrow) * BK + gl * 8]);                 \
    _Pragma("unroll")                                                          \
    for (int m = 0; m < 4; ++m)                                                \
      _Pragma("unroll")                                                        \
      for (int nn = 0; nn < 4; ++nn)                                           \
        acc[m][nn] = __builtin_amdgcn_mfma_f32_16x16x32_bf16(                  \
            af[m], bfr[nn], acc[m][nn], 0, 0, 0);                              \
  }

#define SYNC_STEP()                                                            \
  asm volatile("s_waitcnt vmcnt(0) lgkmcnt(0)" ::: "memory");                  \
  __builtin_amdgcn_s_barrier();                                                \
  __builtin_amdgcn_sched_barrier(0);

__global__ __launch_bounds__(256, 4) void gg6(
    const unsigned short* __restrict__ Xs, const unsigned short* __restrict__ Ws,
    const int* __restrict__ pbase, const int* __restrict__ tinfo,
    const int* __restrict__ ptok, float* __restrict__ out)
{
  __shared__ unsigned short As[2][BM * BK];   // 8 KB per buffer
  __shared__ unsigned short Bs[2][BN * BK];   // total 32 KB

  const int info = tinfo[blockIdx.x];
  if (info < 0) return;
  const int r = info >> 16;
  const int mt = info & 0xFFFF;
  const int ct = blockIdx.y;
  const int prow0 = pbase[r] + mt * BM;

  const int tid = threadIdx.x;
  const int lane = tid & 63;
  const int wid = tid >> 6;
  const int wr = wid >> 1, wc = wid & 1;
  const int lrow = lane & 15;
  const int gl = lane >> 4;
  const int lrow4 = gl * 4;

  // staging addresses: chunk c = k*256 + tid covers LDS bytes c*16;
  // row = c>>2 (64B per row), col granule = (tid&3)*8 elems.
  const unsigned short* asrc0 =
      Xs + (size_t)(prow0 + (tid >> 2)) * EMB + (tid & 3) * 8;
  const unsigned short* asrc1 = asrc0 + (size_t)64 * EMB;
  const unsigned short* bsrc0 =
      Ws + ((size_t)r * EMB + (size_t)(ct * BN + (tid >> 2))) * EMB + (tid & 3) * 8;
  const unsigned short* bsrc1 = bsrc0 + (size_t)64 * EMB;

  f32x4 acc[4][4];
  const f32x4 vzero = {0.f, 0.f, 0.f, 0.f};
  #pragma unroll
  for (int m = 0; m < 4; ++m)
    #pragma unroll
    for (int nn = 0; nn < 4; ++nn) acc[m][nn] = vzero;

  STAGE(0, 0);
  SYNC_STEP();

  #pragma unroll
  for (int kt2 = 0; kt2 < NKT / 2; ++kt2) {
    const int kte = kt2 * 2;
    if (kte + 1 < NKT) STAGE(1, kte + 1);   // prefetch into buf1
    COMPUTE(0);                              // compute buf0 (loads in flight)
    SYNC_STEP();
    if (kte + 2 < NKT) STAGE(0, kte + 2);   // prefetch into buf0
    COMPUTE(1);                              // compute buf1
    SYNC_STEP();
  }

  // Epilogue: D mapping col=lane&15, row=(lane>>4)*4+reg
  #pragma unroll
  for (int m = 0; m < 4; ++m) {
    const int base = prow0 + wr * 64 + m * 16 + lrow4;
    #pragma unroll
    for (int rg = 0; rg < 4; ++rg) {
      const int tok = ptok[base + rg];
      if (tok >= 0) {
        float* orow = out + (size_t)tok * EMB + ct * BN + wc * 64;
        #pragma unroll
        for (int nn = 0; nn < 4; ++nn)
          orow[nn * 16 + lrow] = acc[m][nn][rg];
      }
    }
  }
}

// Safety-net naive kernel (only if ws too small).
__global__ void naive_kernel(const float* __restrict__ X, const int* __restrict__ rel,
                             const float* __restrict__ W, float* __restrict__ out, int n) {
  int i = blockIdx.x;
  if (i >= n) return;
  int r = rel[i];
  const float* x = X + (size_t)i * EMB;
  const float* Wr = W + (size_t)r * EMB * EMB;
  for (int j = threadIdx.x; j < EMB; j += blockDim.x) {
    const float* w = Wr + (size_t)j * EMB;
    float s = 0.f;
    for (int k = 0; k < EMB; ++k) s += w[k] * x[k];
    out[(size_t)i * EMB + j] = s;
  }
}

extern "C" void kernel_launch(void* const* d_in, const int* in_sizes, int n_in,
                              void* d_out, int out_size, void* d_ws, size_t ws_size,
                              hipStream_t stream) {
  const float* X  = (const float*)d_in[0];
  const int* rel  = (const int*)d_in[1];
  const float* W  = (const float*)d_in[2];
  float* out      = (float*)d_out;
  const int n = in_sizes[1];
  const int welems = in_sizes[2];                 // n_rel * EMB * EMB
  const int padn = n + N_RELC * BM;
  const int maxt = (n + BM - 1) / BM + N_RELC;
  const int maxtp = ((maxt + 7) / 8) * 8;         // multiple of 8 (XCD co-location)

  const size_t ints = (size_t)64 + n + padn + maxtp;
  const size_t offW = ((ints * sizeof(int) + 255) / 256) * 256;
  const size_t offX = offW + (((size_t)welems * 2 + 255) / 256) * 256;
  const size_t need = offX + (size_t)padn * EMB * 2;

  if (ws_size < need) {
    naive_kernel<<<n, 256, 0, stream>>>(X, rel, W, out, n);
    return;
  }

  int* cnt   = (int*)d_ws;       // 16 (+pad)
  int* pbase = cnt + 16;         // 17
  int* pos   = cnt + 64;         // n
  int* ptok  = pos + n;          // padn
  int* tinfo = ptok + padn;      // maxtp
  unsigned short* Ws = (unsigned short*)((char*)d_ws + offW);
  unsigned short* Xs = (unsigned short*)((char*)d_ws + offX);

  const int gb = (n + 3) / 4;                       // gather blocks
  const int wb = (welems / 8 + 255) / 256;          // convert-W blocks

  init_counts<<<1, 32, 0, stream>>>(cnt);
  histo_rank_fill<<<(padn + 255) / 256, 256, 0, stream>>>(rel, cnt, pos, ptok, n, padn);
  prefix_tiles64<<<1, 64, 0, stream>>>(cnt, pbase, tinfo, maxtp);
  prep_all<<<gb + N_RELC + wb, 256, 0, stream>>>(X, W, rel, pos, pbase, cnt,
                                                 Xs, Ws, ptok, n, welems, gb);

  // grid.x = m-tiles (multiple of 8), grid.y = 4 column tiles: the 4 ct
  // blocks of one m-tile share blockIdx.x % 8 -> same XCD L2 (X reuse).
  dim3 grid(maxtp, EMB / BN);
  gg6<<<grid, 256, 0, stream>>>(Xs, Ws, pbase, tinfo, ptok, out);
}